// Round 9
// baseline (316.924 us; speedup 1.0000x reference)
//
#include <hip/hip_runtime.h>
#include <hip/hip_bf16.h>

#define SS 256
#define DQd 64
#define DVd 128
#define MMd 50
#define FFd 128
#define CH 64          // steps per chunk

typedef __hip_bfloat16 bf16;
typedef __attribute__((ext_vector_type(8))) short v8s;
typedef __attribute__((ext_vector_type(4))) float v4f;

__device__ __forceinline__ float b2f(bf16 x){ return __bfloat162float(x); }
__device__ __forceinline__ bf16 f2b(float x){ return __float2bfloat16(x); }

__device__ __forceinline__ float ldf(const void* p, long i, int isbf) {
    return isbf ? __bfloat162float(((const bf16*)p)[i]) : ((const float*)p)[i];
}

__device__ __forceinline__ v8s load_frag8(const void* base, long off, int isbf) {
    if (isbf) return *(const v8s*)((const bf16*)base + off);
    const float* f = (const float*)base + off;
    union { bf16 h[8]; v8s v; } u;
    #pragma unroll
    for (int j = 0; j < 8; ++j) u.h[j] = f2b(f[j]);
    return u.v;
}

__device__ __forceinline__ float bflo(unsigned int u){ union{unsigned int i;float f;}c; c.i = u << 16; return c.f; }
__device__ __forceinline__ float bfhi(unsigned int u){ union{unsigned int i;float f;}c; c.i = u & 0xFFFF0000u; return c.f; }

__device__ __forceinline__ float2 pkfma(float2 a, float2 b, float2 c) {
    return make_float2(__builtin_fmaf(a.x, b.x, c.x), __builtin_fmaf(a.y, b.y, c.y));
}

__device__ __forceinline__ float tanh_c(float x) {
    x = fminf(fmaxf(x, -10.f), 10.f);
    float e = __expf(2.f * x);
    return (e - 1.f) / (e + 1.f);
}

// ---- fp32 conv region offsets (floats) ----
#define OFFF_INIT    0        // init_value 50*128 = 6400
#define OFFF_BIASCAT 6400     // b_e | b_a = 256
#define OFFF_BREAD   6656     // 128
#define OFFF_WPRED   6784     // 128
#define OFFF_BPRED   6912     // 1
#define CONVF_TOTAL  7168

// ---- bf16 conv region offsets (elements) ----
#define BO_WTCAT 0            // W_cat^T [256 n][128 k] = 32768
#define BO_KM    32768        // km padded [64 rows][64 k] = 4096
#define BO_WRT   36864        // W_read^T [128 n][192 k] = 24576
#define CONVB_TOTAL 61440

// ---------------- Phase 0a: detect input dtype ----------------
__global__ __launch_bounds__(256) void detect_dtype(const void* W_e, int* flag)
{
    __shared__ float mx[256];
    const int tid = threadIdx.x;
    const bf16* p = (const bf16*)W_e;
    float m = 0.f;
    for (int i = tid; i < 4096; i += 256) {
        float v = b2f(p[i]);
        float a = fabsf(v);
        if (!(a < 1e30f)) a = 1e30f;
        m = fmaxf(m, a);
    }
    mx[tid] = m; __syncthreads();
    for (int s = 128; s > 0; s >>= 1) {
        if (tid < s) mx[tid] = fmaxf(mx[tid], mx[tid + s]);
        __syncthreads();
    }
    if (tid == 0) flag[0] = (mx[0] < 16.0f) ? 1 : 0;
}

// ---------------- Phase 0b: build fp32 + bf16(transposed) weight scratch ----------------
__global__ __launch_bounds__(256) void conv_weights(
    const void* km, const void* initv, const void* We, const void* be,
    const void* Wa, const void* ba, const void* Wr, const void* br,
    const void* Wp, const void* bp, const int* flag,
    float* convf, bf16* convb)
{
    const int isbf = flag[0];
    int i = blockIdx.x * 256 + threadIdx.x;
    if (i < CONVF_TOTAL) {
        float v = 0.f;
        if      (i < 6400) v = ldf(initv, i, isbf);
        else if (i < 6528) v = ldf(be, i - 6400, isbf);
        else if (i < 6656) v = ldf(ba, i - 6528, isbf);
        else if (i < 6784) v = ldf(br, i - 6656, isbf);
        else if (i < 6912) v = ldf(Wp, i - 6784, isbf);
        else if (i == 6912) v = ldf(bp, 0, isbf);
        convf[i] = v;
    } else {
        int j = i - CONVF_TOTAL;
        if (j >= CONVB_TOTAL) return;
        float v;
        if (j < 32768) {                       // W_cat^T: [n][k] <- We/Wa [k][n]
            int n = j >> 7, k = j & 127;
            v = (n < 128) ? ldf(We, (long)k * 128 + n, isbf)
                          : ldf(Wa, (long)k * 128 + (n - 128), isbf);
        } else if (j < 36864) {                // km padded
            int j2 = j - 32768;
            int row = j2 >> 6, k = j2 & 63;
            v = (row < MMd) ? ldf(km, (long)row * 64 + k, isbf) : 0.f;
        } else {                               // W_read^T
            int j3 = j - 36864;
            int n = j3 / 192, k = j3 - n * 192;
            v = ldf(Wr, (long)k * 128 + n, isbf);
        }
        convb[j] = f2b(v);
    }
}

// ---------------- Fused kernel: per-batch GEMMs -> scan -> readout, all via LDS ----------
// 256 blocks (one batch each, 1/CU) x 512 threads (8 waves).
// Per 64-step chunk: (1) GEMM role: waves compute e/a (MFMA) + w/softmax into padded LDS;
// (2) scan role: register-resident scan reads LDS only; (3) p3 role: waves 0-3 run the
// readout GEMM on LDS reads -> probs + BCE partials. No inter-phase HBM workspace.
__global__ __launch_bounds__(512, 1) void fused(
    const int* __restrict__ q_data, const int* __restrict__ qa_data,
    const void* __restrict__ q_table, const void* __restrict__ qa_table,
    const void* __restrict__ target,
    const float* __restrict__ convf, const bf16* __restrict__ convb,
    const int* __restrict__ flag,
    void* __restrict__ out, float* __restrict__ accum)
{
    __shared__ __attribute__((aligned(16))) bf16  e_c[CH][132];    // +4 pad
    __shared__ __attribute__((aligned(16))) bf16  a_c[CH][132];
    __shared__ __attribute__((aligned(16))) float w_c[CH][68];     // +4 pad
    __shared__ __attribute__((aligned(16))) bf16  reads_c[CH][136];// +8 pad
    __shared__ float bsum[4], csum[4];

    const int tid = threadIdx.x;
    const int lane = tid & 63;
    const int wv = tid >> 6;          // wave 0..7
    const int c = lane & 15;
    const int quad = lane >> 4;
    const int isbf = flag[0];
    const long r0 = (long)blockIdx.x * SS;

    // scan-role ids
    const int d  = tid >> 2;          // 0..127
    const int qm = tid & 3;
    const int mo = qm * 16;

    float2 mem2[8];
    {
        float* mf = (float*)mem2;
        #pragma unroll
        for (int i = 0; i < 16; ++i) {
            int m = mo + i;
            mf[i] = (m < MMd) ? convf[OFFF_INIT + m * DVd + d] : 0.f;
        }
    }

    float bce_acc = 0.f, cnt_acc = 0.f;

    for (int ch = 0; ch < SS / CH; ++ch) {
        const long rc = r0 + (long)ch * CH;

        // ================= GEMM role: build w/e/a for this chunk =================
        {
            const int mt = wv & 3;        // row-tile 0..3
            const int half = wv >> 2;     // 0: e-cols, 1: a-cols
            const long gr = rc + mt * 16 + c;
            const int qa_idx = qa_data[gr];
            const int q_idx  = q_data[gr];

            v4f acc[8];
            #pragma unroll
            for (int nt = 0; nt < 8; ++nt) acc[nt] = (v4f){0.f, 0.f, 0.f, 0.f};
            #pragma unroll
            for (int ks = 0; ks < 4; ++ks) {
                v8s x = load_frag8(qa_table, (long)qa_idx * DVd + ks * 32 + quad * 8, isbf);
                #pragma unroll
                for (int nt = 0; nt < 8; ++nt) {
                    v8s wf = *(const v8s*)(convb + BO_WTCAT +
                               (long)((half * 8 + nt) * 16 + c) * 128 + ks * 32 + quad * 8);
                    acc[nt] = __builtin_amdgcn_mfma_f32_16x16x32_bf16(wf, x, acc[nt], 0, 0, 0);
                }
            }
            // epilogue: lane owns 4 consecutive cols of row (mt*16+c)
            const int row = mt * 16 + c;
            #pragma unroll
            for (int nt = 0; nt < 8; ++nt) {
                const int col0 = (half * 8 + nt) * 16 + quad * 4;   // global col
                float4 b4 = *(const float4*)(convf + OFFF_BIASCAT + col0);
                const float bb[4] = {b4.x, b4.y, b4.z, b4.w};
                union { bf16 h[4]; uint2 u; } pk;
                #pragma unroll
                for (int i = 0; i < 4; ++i) {
                    float v = acc[nt][i] + bb[i];
                    pk.h[i] = (half == 0) ? f2b(1.f / (1.f + __expf(-v))) : f2b(tanh_c(v));
                }
                if (half == 0) *(uint2*)&e_c[row][col0]       = pk.u;
                else           *(uint2*)&a_c[row][col0 - 128] = pk.u;
            }

            // attention + softmax: waves 0-3 only
            if (half == 0) {
                v4f sc[4];
                #pragma unroll
                for (int nt = 0; nt < 4; ++nt) sc[nt] = (v4f){0.f, 0.f, 0.f, 0.f};
                #pragma unroll
                for (int ks = 0; ks < 2; ++ks) {
                    v8s x = load_frag8(q_table, (long)q_idx * DQd + ks * 32 + quad * 8, isbf);
                    #pragma unroll
                    for (int nt = 0; nt < 4; ++nt) {
                        v8s kf = *(const v8s*)(convb + BO_KM +
                                   (long)(nt * 16 + c) * 64 + ks * 32 + quad * 8);
                        sc[nt] = __builtin_amdgcn_mfma_f32_16x16x32_bf16(kf, x, sc[nt], 0, 0, 0);
                    }
                }
                float mx = -1e30f;
                #pragma unroll
                for (int nt = 0; nt < 4; ++nt)
                    #pragma unroll
                    for (int i = 0; i < 4; ++i) {
                        bool valid = (nt < 3) || (quad == 0 && i < 2);
                        if (valid) mx = fmaxf(mx, sc[nt][i]);
                    }
                mx = fmaxf(mx, __shfl_xor(mx, 16, 64));
                mx = fmaxf(mx, __shfl_xor(mx, 32, 64));
                float ex[4][4];
                float sm = 0.f;
                #pragma unroll
                for (int nt = 0; nt < 4; ++nt)
                    #pragma unroll
                    for (int i = 0; i < 4; ++i) {
                        bool valid = (nt < 3) || (quad == 0 && i < 2);
                        float e = valid ? __expf(sc[nt][i] - mx) : 0.f;
                        ex[nt][i] = e;
                        sm += e;
                    }
                sm += __shfl_xor(sm, 16, 64);
                sm += __shfl_xor(sm, 32, 64);
                float inv = 1.f / sm;
                #pragma unroll
                for (int nt = 0; nt < 4; ++nt) {
                    float4 wv4 = make_float4(ex[nt][0]*inv, ex[nt][1]*inv,
                                             ex[nt][2]*inv, ex[nt][3]*inv);
                    *(float4*)&w_c[row][nt * 16 + quad * 4] = wv4;
                }
            }
        }
        __syncthreads();

        // ================= scan role: 64 steps, LDS-only reads =================
        {
            const unsigned long long flags = __ballot(q_data[rc + lane] >= 1);
            #pragma unroll 4
            for (int tt = 0; tt < CH; ++tt) {
                float4 w4[4];
                #pragma unroll
                for (int k = 0; k < 4; ++k) w4[k] = *(const float4*)&w_c[tt][mo + 4*k];
                const float2* w2 = (const float2*)w4;
                const float e = b2f(e_c[tt][d]);
                const float a = b2f(a_c[tt][d]);

                float2 s2a = {0.f, 0.f}, s2b = {0.f, 0.f};
                #pragma unroll
                for (int i = 0; i < 4; ++i) {
                    s2a = pkfma(w2[2*i],     mem2[2*i],     s2a);
                    s2b = pkfma(w2[2*i + 1], mem2[2*i + 1], s2b);
                }
                float acc = (s2a.x + s2a.y) + (s2b.x + s2b.y);
                acc += __shfl_xor(acc, 1, 64);
                acc += __shfl_xor(acc, 2, 64);
                if (qm == 0) reads_c[tt][d] = f2b(acc);

                if ((flags >> tt) & 1ULL) {
                    const float2 a2 = {a, a}, en2 = {-e, -e};
                    #pragma unroll
                    for (int i = 0; i < 8; ++i) {
                        float2 t = pkfma(en2, mem2[i], a2);
                        mem2[i] = pkfma(w2[i], t, mem2[i]);
                    }
                }
            }
        }
        __syncthreads();

        // ================= p3 role: readout GEMM for this chunk (waves 0-3) =====
        if (wv < 4) {
            const long gr3 = rc + wv * 16 + c;
            const int q3 = q_data[gr3];
            v4f acc3[8];
            #pragma unroll
            for (int nt = 0; nt < 8; ++nt) acc3[nt] = (v4f){0.f, 0.f, 0.f, 0.f};
            #pragma unroll
            for (int ks = 0; ks < 6; ++ks) {
                v8s x;
                if (ks < 4) x = *(const v8s*)&reads_c[wv * 16 + c][ks * 32 + quad * 8];
                else        x = load_frag8(q_table, (long)q3 * DQd + (ks - 4) * 32 + quad * 8, isbf);
                #pragma unroll
                for (int nt = 0; nt < 8; ++nt) {
                    v8s wf = *(const v8s*)(convb + BO_WRT +
                               (long)(nt * 16 + c) * 192 + ks * 32 + quad * 8);
                    acc3[nt] = __builtin_amdgcn_mfma_f32_16x16x32_bf16(wf, x, acc3[nt], 0, 0, 0);
                }
            }
            float pp = 0.f;
            #pragma unroll
            for (int nt = 0; nt < 8; ++nt) {
                const int col0 = nt * 16 + quad * 4;
                float4 br4 = *(const float4*)(convf + OFFF_BREAD + col0);
                float4 wp4 = *(const float4*)(convf + OFFF_WPRED + col0);
                const float br[4] = {br4.x, br4.y, br4.z, br4.w};
                const float wp[4] = {wp4.x, wp4.y, wp4.z, wp4.w};
                #pragma unroll
                for (int i = 0; i < 4; ++i)
                    pp += tanh_c(acc3[nt][i] + br[i]) * wp[i];
            }
            pp += __shfl_xor(pp, 16, 64);
            pp += __shfl_xor(pp, 32, 64);

            float logit = pp + convf[OFFF_BPRED];
            float prob = 1.f / (1.f + __expf(-logit));
            if (quad == 0) {
                if (isbf) ((bf16*)out)[1 + gr3] = f2b(prob);
                else      ((float*)out)[1 + gr3] = prob;
                float tg = ldf(target, gr3, isbf);
                bool mask = tg >= 0.f;
                float bce = fmaxf(logit, 0.f) - logit * tg + log1pf(__expf(-fabsf(logit)));
                bce_acc += mask ? bce : 0.f;
                cnt_acc += mask ? 1.f : 0.f;
            }
        }
        __syncthreads();
    }

    // final BCE reduction: contributors are waves 0-3, quad==0 lanes (c = 0..15)
    if (wv < 4 && quad == 0) {
        float sb = bce_acc, sc2 = cnt_acc;
        #pragma unroll
        for (int m = 1; m <= 8; m <<= 1) {
            sb  += __shfl_xor(sb,  m, 64);
            sc2 += __shfl_xor(sc2, m, 64);
        }
        if (c == 0) { bsum[wv] = sb; csum[wv] = sc2; }
    }
    __syncthreads();
    if (tid == 0) {
        atomicAdd(&accum[0], bsum[0] + bsum[1] + bsum[2] + bsum[3]);
        atomicAdd(&accum[1], csum[0] + csum[1] + csum[2] + csum[3]);
    }
}

// ---------------- Finalize loss ----------------
__global__ void phase4(const float* __restrict__ accum, const int* __restrict__ flag,
                       void* __restrict__ out)
{
    if (threadIdx.x == 0 && blockIdx.x == 0) {
        float n = fmaxf(accum[1], 1.f);
        float loss = accum[0] / n;
        if (flag[0]) ((bf16*)out)[0] = f2b(loss);
        else         ((float*)out)[0] = loss;
    }
}

extern "C" void kernel_launch(void* const* d_in, const int* in_sizes, int n_in,
                              void* d_out, int out_size, void* d_ws, size_t ws_size,
                              hipStream_t stream) {
    (void)in_sizes; (void)n_in; (void)out_size; (void)ws_size;

    const int*  q_data   = (const int*) d_in[0];
    const int*  qa_data  = (const int*) d_in[1];
    const void* target   = d_in[2];
    const void* q_table  = d_in[3];
    const void* qa_table = d_in[4];
    const void* key_mem  = d_in[5];
    const void* init_val = d_in[6];
    const void* W_e      = d_in[7];
    const void* b_e      = d_in[8];
    const void* W_a      = d_in[9];
    const void* b_a      = d_in[10];
    const void* W_read   = d_in[11];
    const void* b_read   = d_in[12];
    const void* W_pred   = d_in[13];
    const void* b_pred   = d_in[14];

    char* ws = (char*)d_ws;
    int*   flag  = (int*)  ws;
    float* accum = (float*)(ws + 64);
    float* convf = (float*)(ws + 256);
    bf16*  convb = (bf16*) (ws + 256 + CONVF_TOTAL * 4);

    hipMemsetAsync(accum, 0, 2 * sizeof(float), stream);

    detect_dtype<<<1, 256, 0, stream>>>(W_e, flag);
    conv_weights<<<(CONVF_TOTAL + CONVB_TOTAL + 255) / 256, 256, 0, stream>>>(
        key_mem, init_val, W_e, b_e, W_a, b_a, W_read, b_read, W_pred, b_pred,
        flag, convf, convb);
    fused<<<256, 512, 0, stream>>>(q_data, qa_data, q_table, qa_table, target,
                                   convf, convb, flag, d_out, accum);
    phase4<<<1, 64, 0, stream>>>(accum, flag, d_out);
}

// Round 10
// 217.749 us; speedup vs baseline: 1.4555x; 1.4555x over previous
//
#include <hip/hip_runtime.h>
#include <hip/hip_bf16.h>

#define SS 256
#define DQd 64
#define DVd 128
#define MMd 50
#define FFd 128
#define CH 64          // phase2 steps per staged chunk

typedef __hip_bfloat16 bf16;
typedef __attribute__((ext_vector_type(8))) short v8s;
typedef __attribute__((ext_vector_type(4))) float v4f;

__device__ __forceinline__ float b2f(bf16 x){ return __bfloat162float(x); }
__device__ __forceinline__ bf16 f2b(float x){ return __float2bfloat16(x); }

__device__ __forceinline__ float ldf(const void* p, long i, int isbf) {
    return isbf ? __bfloat162float(((const bf16*)p)[i]) : ((const float*)p)[i];
}

__device__ __forceinline__ v8s load_frag8(const void* base, long off, int isbf) {
    if (isbf) return *(const v8s*)((const bf16*)base + off);
    const float* f = (const float*)base + off;
    union { bf16 h[8]; v8s v; } u;
    #pragma unroll
    for (int j = 0; j < 8; ++j) u.h[j] = f2b(f[j]);
    return u.v;
}

__device__ __forceinline__ float bflo(unsigned int u){ union{unsigned int i;float f;}c; c.i = u << 16; return c.f; }
__device__ __forceinline__ float bfhi(unsigned int u){ union{unsigned int i;float f;}c; c.i = u & 0xFFFF0000u; return c.f; }

__device__ __forceinline__ float2 pkfma(float2 a, float2 b, float2 c) {
    return make_float2(__builtin_fmaf(a.x, b.x, c.x), __builtin_fmaf(a.y, b.y, c.y));
}

__device__ __forceinline__ float tanh_c(float x) {
    x = fminf(fmaxf(x, -10.f), 10.f);
    float e = __expf(2.f * x);
    return (e - 1.f) / (e + 1.f);
}

// ---- fp32 conv region offsets (floats) ----
#define OFFF_INIT    0        // init_value 50*128 = 6400
#define OFFF_BIASCAT 6400     // b_e | b_a = 256
#define OFFF_BREAD   6656     // 128
#define OFFF_WPRED   6784     // 128
#define OFFF_BPRED   6912     // 1
#define CONVF_TOTAL  7168

// ---- bf16 conv region offsets (elements) ----
#define BO_WTCAT 0            // W_cat^T [256 n][128 k] = 32768
#define BO_KM    32768        // km padded [64 rows][64 k] = 4096
#define BO_WRT   36864        // W_read^T [128 n][192 k] = 24576
#define CONVB_TOTAL 61440

// ---------------- Phase 0a: detect input dtype ----------------
__global__ __launch_bounds__(256) void detect_dtype(const void* W_e, int* flag)
{
    __shared__ float mx[256];
    const int tid = threadIdx.x;
    const bf16* p = (const bf16*)W_e;
    float m = 0.f;
    for (int i = tid; i < 4096; i += 256) {
        float v = b2f(p[i]);
        float a = fabsf(v);
        if (!(a < 1e30f)) a = 1e30f;
        m = fmaxf(m, a);
    }
    mx[tid] = m; __syncthreads();
    for (int s = 128; s > 0; s >>= 1) {
        if (tid < s) mx[tid] = fmaxf(mx[tid], mx[tid + s]);
        __syncthreads();
    }
    if (tid == 0) flag[0] = (mx[0] < 16.0f) ? 1 : 0;
}

// ---------------- Phase 0b: build fp32 + bf16(transposed) weight scratch ----------------
__global__ __launch_bounds__(256) void conv_weights(
    const void* km, const void* initv, const void* We, const void* be,
    const void* Wa, const void* ba, const void* Wr, const void* br,
    const void* Wp, const void* bp, const int* flag,
    float* convf, bf16* convb)
{
    const int isbf = flag[0];
    int i = blockIdx.x * 256 + threadIdx.x;
    if (i < CONVF_TOTAL) {
        float v = 0.f;
        if      (i < 6400) v = ldf(initv, i, isbf);
        else if (i < 6528) v = ldf(be, i - 6400, isbf);
        else if (i < 6656) v = ldf(ba, i - 6528, isbf);
        else if (i < 6784) v = ldf(br, i - 6656, isbf);
        else if (i < 6912) v = ldf(Wp, i - 6784, isbf);
        else if (i == 6912) v = ldf(bp, 0, isbf);
        convf[i] = v;
    } else {
        int j = i - CONVF_TOTAL;
        if (j >= CONVB_TOTAL) return;
        float v;
        if (j < 32768) {                       // W_cat^T: [n][k] <- We/Wa [k][n]
            int n = j >> 7, k = j & 127;
            v = (n < 128) ? ldf(We, (long)k * 128 + n, isbf)
                          : ldf(Wa, (long)k * 128 + (n - 128), isbf);
        } else if (j < 36864) {                // km padded
            int j2 = j - 32768;
            int row = j2 >> 6, k = j2 & 63;
            v = (row < MMd) ? ldf(km, (long)row * 64 + k, isbf) : 0.f;
        } else {                               // W_read^T
            int j3 = j - 36864;
            int n = j3 / 192, k = j3 - n * 192;
            v = ldf(Wr, (long)k * 128 + n, isbf);
        }
        convb[j] = f2b(v);
    }
}

// ---------------- Phase 1: 128 rows/block, LDS-staged W, preloaded A-frags ----------------
__global__ __launch_bounds__(512, 4) void phase1(
    const int* __restrict__ q_data, const int* __restrict__ qa_data,
    const void* __restrict__ q_table, const void* __restrict__ qa_table,
    const float* __restrict__ convf, const bf16* __restrict__ convb,
    const int* __restrict__ flag,
    bf16* __restrict__ w_ws, bf16* __restrict__ e_ws, bf16* __restrict__ a_ws)
{
    __shared__ __attribute__((aligned(16))) bf16 WT_s[256][136];  // +8 pad
    __shared__ __attribute__((aligned(16))) bf16 km_s[64][72];

    const int tid = threadIdx.x;
    const int lane = tid & 63;
    const int strip = tid >> 6;          // wave 0..7 = row-tile
    const int c = lane & 15;
    const int quad = lane >> 4;
    const int r0 = blockIdx.x * 128;
    const int isbf = flag[0];

    const long gr = r0 + strip * 16 + c;
    const int qa_idx = qa_data[gr];
    const int q_idx  = q_data[gr];

    // preload A-fragments (global gathers in flight during LDS staging)
    v8s f_qa[4], f_q[2];
    #pragma unroll
    for (int ks = 0; ks < 4; ++ks)
        f_qa[ks] = load_frag8(qa_table, (long)qa_idx * DVd + ks * 32 + quad * 8, isbf);
    #pragma unroll
    for (int ks = 0; ks < 2; ++ks)
        f_q[ks] = load_frag8(q_table, (long)q_idx * DQd + ks * 32 + quad * 8, isbf);

    // stage W_cat^T + km into padded LDS
    #pragma unroll
    for (int it = 0; it < 8; ++it) {
        int i = tid * 8 + it * 4096;
        int n = i >> 7, k = i & 127;
        *(v8s*)&WT_s[n][k] = *(const v8s*)(convb + BO_WTCAT + i);
    }
    {
        int i = tid * 8;
        int row = i >> 6, k = i & 63;
        *(v8s*)&km_s[row][k] = *(const v8s*)(convb + BO_KM + i);
    }
    __syncthreads();

    // ---- GEMM1: W_cat as A-operand, qa emb as B-operand
    v4f acc[16];
    #pragma unroll
    for (int nt = 0; nt < 16; ++nt) acc[nt] = (v4f){0.f, 0.f, 0.f, 0.f};
    #pragma unroll
    for (int ks = 0; ks < 4; ++ks) {
        #pragma unroll
        for (int nt = 0; nt < 16; ++nt) {
            v8s wf = *(const v8s*)&WT_s[nt * 16 + c][ks * 32 + quad * 8];
            acc[nt] = __builtin_amdgcn_mfma_f32_16x16x32_bf16(wf, f_qa[ks], acc[nt], 0, 0, 0);
        }
    }
    #pragma unroll
    for (int nt = 0; nt < 16; ++nt) {
        const int col0 = nt * 16 + quad * 4;
        float4 b4 = *(const float4*)(convf + OFFF_BIASCAT + col0);
        const float bb[4] = {b4.x, b4.y, b4.z, b4.w};
        union { bf16 h[4]; uint2 u; } pk;
        #pragma unroll
        for (int i = 0; i < 4; ++i) {
            float v = acc[nt][i] + bb[i];
            pk.h[i] = (nt < 8) ? f2b(1.f / (1.f + __expf(-v))) : f2b(tanh_c(v));
        }
        if (nt < 8) *(uint2*)(e_ws + gr * DVd + col0)         = pk.u;
        else        *(uint2*)(a_ws + gr * DVd + (col0 - 128)) = pk.u;
    }

    // ---- GEMM2: km as A-operand, q emb as B-operand
    v4f sc[4];
    #pragma unroll
    for (int nt = 0; nt < 4; ++nt) sc[nt] = (v4f){0.f, 0.f, 0.f, 0.f};
    #pragma unroll
    for (int ks = 0; ks < 2; ++ks) {
        #pragma unroll
        for (int nt = 0; nt < 4; ++nt) {
            v8s kf = *(const v8s*)&km_s[nt * 16 + c][ks * 32 + quad * 8];
            sc[nt] = __builtin_amdgcn_mfma_f32_16x16x32_bf16(kf, f_q[ks], sc[nt], 0, 0, 0);
        }
    }
    // softmax over this row's 50 cols; lane holds cols nt*16+quad*4+i
    float mx = -1e30f;
    #pragma unroll
    for (int nt = 0; nt < 4; ++nt)
        #pragma unroll
        for (int i = 0; i < 4; ++i) {
            bool valid = (nt < 3) || (quad == 0 && i < 2);
            if (valid) mx = fmaxf(mx, sc[nt][i]);
        }
    mx = fmaxf(mx, __shfl_xor(mx, 16, 64));
    mx = fmaxf(mx, __shfl_xor(mx, 32, 64));
    float ex[4][4];
    float sm = 0.f;
    #pragma unroll
    for (int nt = 0; nt < 4; ++nt)
        #pragma unroll
        for (int i = 0; i < 4; ++i) {
            bool valid = (nt < 3) || (quad == 0 && i < 2);
            float e = valid ? __expf(sc[nt][i] - mx) : 0.f;
            ex[nt][i] = e;
            sm += e;
        }
    sm += __shfl_xor(sm, 16, 64);
    sm += __shfl_xor(sm, 32, 64);
    float inv = 1.f / sm;
    #pragma unroll
    for (int nt = 0; nt < 4; ++nt) {
        union { bf16 h[4]; uint2 u; } pk;
        #pragma unroll
        for (int i = 0; i < 4; ++i) pk.h[i] = f2b(ex[nt][i] * inv);
        *(uint2*)(w_ws + gr * 64 + nt * 16 + quad * 4) = pk.u;
    }
}

// ---------------- Phase 2: register scan + LDS chunks; ballot flags, shfl reduce ----
__global__ __launch_bounds__(512, 1) void phase2(
    const int* __restrict__ q_data,
    const float* __restrict__ convf,
    const bf16* __restrict__ w_ws, const bf16* __restrict__ e_ws,
    const bf16* __restrict__ a_ws, bf16* __restrict__ reads_ws)
{
    __shared__ __attribute__((aligned(16))) float        w_s[2][CH][64];    // 32 KB
    __shared__ __attribute__((aligned(16))) unsigned int ea_s[2][CH][DVd];  // 64 KB

    const int tid = threadIdx.x;
    const int lane = tid & 63;
    const int d  = tid >> 2;
    const int qm = tid & 3;
    const int mo = qm * 16;
    const long r0 = (long)blockIdx.x * SS;

    float2 mem2[8];
    {
        float* mf = (float*)mem2;
        #pragma unroll
        for (int i = 0; i < 16; ++i) {
            int m = mo + i;
            mf[i] = (m < MMd) ? convf[OFFF_INIT + m * DVd + d] : 0.f;
        }
    }

    // ---- stage chunk 0
    {
        uint4 wst = *(const uint4*)((const char*)(w_ws + r0 * 64) + tid * 16);
        const char* es = (const char*)(e_ws + r0 * DVd);
        const char* as = (const char*)(a_ws + r0 * DVd);
        uint4 e0 = *(const uint4*)(es + tid * 32);
        uint4 e1 = *(const uint4*)(es + tid * 32 + 16);
        uint4 a0 = *(const uint4*)(as + tid * 32);
        uint4 a1 = *(const uint4*)(as + tid * 32 + 16);
        float wf[8];
        const unsigned int* wu = (const unsigned int*)&wst;
        #pragma unroll
        for (int j = 0; j < 4; ++j) { wf[2*j] = bflo(wu[j]); wf[2*j+1] = bfhi(wu[j]); }
        *(float4*)((char*)&w_s[0][0][0] + tid * 32)      = *(float4*)&wf[0];
        *(float4*)((char*)&w_s[0][0][0] + tid * 32 + 16) = *(float4*)&wf[4];
        unsigned int ea[16];
        unsigned int ebuf[8] = {e0.x,e0.y,e0.z,e0.w,e1.x,e1.y,e1.z,e1.w};
        unsigned int abuf[8] = {a0.x,a0.y,a0.z,a0.w,a1.x,a1.y,a1.z,a1.w};
        #pragma unroll
        for (int j = 0; j < 8; ++j) {
            ea[2*j]   = (ebuf[j] & 0xFFFFu) | (abuf[j] << 16);
            ea[2*j+1] = (ebuf[j] >> 16) | (abuf[j] & 0xFFFF0000u);
        }
        #pragma unroll
        for (int j = 0; j < 4; ++j)
            *(uint4*)((char*)&ea_s[0][0][0] + tid * 64 + j * 16) = *(uint4*)&ea[4*j];
    }
    __syncthreads();

    int buf = 0;
    for (int c = 0; c < SS / CH; ++c) {
        const int nb = buf ^ 1;
        const bool more = (c + 1 < SS / CH);

        uint4 wst, e0, e1, a0, a1;
        if (more) {
            long rn = r0 + (long)(c + 1) * CH;
            wst = *(const uint4*)((const char*)(w_ws + rn * 64) + tid * 16);
            const char* es = (const char*)(e_ws + rn * DVd);
            const char* as = (const char*)(a_ws + rn * DVd);
            e0 = *(const uint4*)(es + tid * 32);
            e1 = *(const uint4*)(es + tid * 32 + 16);
            a0 = *(const uint4*)(as + tid * 32);
            a1 = *(const uint4*)(as + tid * 32 + 16);
        }

        const unsigned long long flags = __ballot(q_data[r0 + c * CH + lane] >= 1);

        #pragma unroll 4
        for (int tt = 0; tt < CH; ++tt) {
            const long r = r0 + c * CH + tt;
            float4 w4[4];
            #pragma unroll
            for (int k = 0; k < 4; ++k) w4[k] = *(const float4*)&w_s[buf][tt][mo + 4*k];
            const float2* w2 = (const float2*)w4;
            const unsigned int ea = ea_s[buf][tt][d];
            const float e = bflo(ea), a = bfhi(ea);

            float2 s2a = {0.f, 0.f}, s2b = {0.f, 0.f};
            #pragma unroll
            for (int i = 0; i < 4; ++i) {
                s2a = pkfma(w2[2*i],     mem2[2*i],     s2a);
                s2b = pkfma(w2[2*i + 1], mem2[2*i + 1], s2b);
            }
            float acc = (s2a.x + s2a.y) + (s2b.x + s2b.y);
            acc += __shfl_xor(acc, 1, 64);
            acc += __shfl_xor(acc, 2, 64);
            if (qm == 0) reads_ws[r * (long)DVd + d] = f2b(acc);

            if ((flags >> tt) & 1ULL) {
                const float2 a2 = {a, a}, en2 = {-e, -e};
                #pragma unroll
                for (int i = 0; i < 8; ++i) {
                    float2 t = pkfma(en2, mem2[i], a2);
                    mem2[i] = pkfma(w2[i], t, mem2[i]);
                }
            }
        }

        if (more) {
            float wf[8];
            const unsigned int* wu = (const unsigned int*)&wst;
            #pragma unroll
            for (int j = 0; j < 4; ++j) { wf[2*j] = bflo(wu[j]); wf[2*j+1] = bfhi(wu[j]); }
            *(float4*)((char*)&w_s[nb][0][0] + tid * 32)      = *(float4*)&wf[0];
            *(float4*)((char*)&w_s[nb][0][0] + tid * 32 + 16) = *(float4*)&wf[4];
            unsigned int ea[16];
            unsigned int ebuf[8] = {e0.x,e0.y,e0.z,e0.w,e1.x,e1.y,e1.z,e1.w};
            unsigned int abuf[8] = {a0.x,a0.y,a0.z,a0.w,a1.x,a1.y,a1.z,a1.w};
            #pragma unroll
            for (int j = 0; j < 8; ++j) {
                ea[2*j]   = (ebuf[j] & 0xFFFFu) | (abuf[j] << 16);
                ea[2*j+1] = (ebuf[j] >> 16) | (abuf[j] & 0xFFFF0000u);
            }
            #pragma unroll
            for (int j = 0; j < 4; ++j)
                *(uint4*)((char*)&ea_s[nb][0][0] + tid * 64 + j * 16) = *(uint4*)&ea[4*j];
        }
        __syncthreads();
        buf = nb;
    }
}

// ---------------- Phase 3: 128 rows/block, LDS-staged W_read, preloaded frags ----------
__global__ __launch_bounds__(512, 4) void phase3(
    const int* __restrict__ q_data,
    const void* __restrict__ q_table,
    const bf16* __restrict__ reads_ws,
    const float* __restrict__ convf, const bf16* __restrict__ convb,
    const void* __restrict__ target, const int* __restrict__ flag,
    void* __restrict__ out, float* __restrict__ accum)
{
    __shared__ __attribute__((aligned(16))) bf16 WRT_s[128][200];  // +8 pad
    __shared__ float bsum[8], csum[8];

    const int tid = threadIdx.x;
    const int lane = tid & 63;
    const int strip = tid >> 6;         // wave 0..7 = row-tile
    const int c = lane & 15;
    const int quad = lane >> 4;
    const int r0 = blockIdx.x * 128;
    const int isbf = flag[0];

    const long gr = r0 + strip * 16 + c;
    const int q_idx = q_data[gr];

    // preload A-frags
    v8s f_rd[4], f_q[2];
    #pragma unroll
    for (int ks = 0; ks < 4; ++ks)
        f_rd[ks] = *(const v8s*)(reads_ws + gr * DVd + ks * 32 + quad * 8);
    #pragma unroll
    for (int ks = 0; ks < 2; ++ks)
        f_q[ks] = load_frag8(q_table, (long)q_idx * DQd + ks * 32 + quad * 8, isbf);

    #pragma unroll
    for (int it = 0; it < 6; ++it) {
        int i = tid * 8 + it * 4096;
        int n = i / 192, k = i - n * 192;
        *(v8s*)&WRT_s[n][k] = *(const v8s*)(convb + BO_WRT + i);
    }
    __syncthreads();

    v4f acc[8];
    #pragma unroll
    for (int nt = 0; nt < 8; ++nt) acc[nt] = (v4f){0.f, 0.f, 0.f, 0.f};

    #pragma unroll
    for (int ks = 0; ks < 6; ++ks) {
        v8s x = (ks < 4) ? f_rd[ks] : f_q[ks - 4];
        #pragma unroll
        for (int nt = 0; nt < 8; ++nt) {
            v8s wf = *(const v8s*)&WRT_s[nt * 16 + c][ks * 32 + quad * 8];
            acc[nt] = __builtin_amdgcn_mfma_f32_16x16x32_bf16(wf, x, acc[nt], 0, 0, 0);
        }
    }

    float pp = 0.f;
    #pragma unroll
    for (int nt = 0; nt < 8; ++nt) {
        const int col0 = nt * 16 + quad * 4;
        float4 br4 = *(const float4*)(convf + OFFF_BREAD + col0);
        float4 wp4 = *(const float4*)(convf + OFFF_WPRED + col0);
        const float br[4] = {br4.x, br4.y, br4.z, br4.w};
        const float wp[4] = {wp4.x, wp4.y, wp4.z, wp4.w};
        #pragma unroll
        for (int i = 0; i < 4; ++i)
            pp += tanh_c(acc[nt][i] + br[i]) * wp[i];
    }
    pp += __shfl_xor(pp, 16, 64);
    pp += __shfl_xor(pp, 32, 64);

    float logit = pp + convf[OFFF_BPRED];
    float prob = 1.f / (1.f + __expf(-logit));
    if (quad == 0) {
        if (isbf) ((bf16*)out)[1 + gr] = f2b(prob);
        else      ((float*)out)[1 + gr] = prob;
    }
    float tg = ldf(target, gr, isbf);
    bool mask = tg >= 0.f;
    float bce = fmaxf(logit, 0.f) - logit * tg + log1pf(__expf(-fabsf(logit)));
    float sb = mask ? bce : 0.f;
    float sc = mask ? 1.f : 0.f;
    #pragma unroll
    for (int m = 1; m <= 8; m <<= 1) {
        sb += __shfl_xor(sb, m, 64);
        sc += __shfl_xor(sc, m, 64);
    }
    if (lane == 0) { bsum[strip] = sb; csum[strip] = sc; }
    __syncthreads();
    if (tid == 0) {
        float tb = 0.f, tc = 0.f;
        #pragma unroll
        for (int i = 0; i < 8; ++i) { tb += bsum[i]; tc += csum[i]; }
        atomicAdd(&accum[0], tb);
        atomicAdd(&accum[1], tc);
    }
}

// ---------------- Phase 4: finalize loss ----------------
__global__ void phase4(const float* __restrict__ accum, const int* __restrict__ flag,
                       void* __restrict__ out)
{
    if (threadIdx.x == 0 && blockIdx.x == 0) {
        float n = fmaxf(accum[1], 1.f);
        float loss = accum[0] / n;
        if (flag[0]) ((bf16*)out)[0] = f2b(loss);
        else         ((float*)out)[0] = loss;
    }
}

extern "C" void kernel_launch(void* const* d_in, const int* in_sizes, int n_in,
                              void* d_out, int out_size, void* d_ws, size_t ws_size,
                              hipStream_t stream) {
    (void)in_sizes; (void)n_in; (void)out_size; (void)ws_size;

    const int*  q_data   = (const int*) d_in[0];
    const int*  qa_data  = (const int*) d_in[1];
    const void* target   = d_in[2];
    const void* q_table  = d_in[3];
    const void* qa_table = d_in[4];
    const void* key_mem  = d_in[5];
    const void* init_val = d_in[6];
    const void* W_e      = d_in[7];
    const void* b_e      = d_in[8];
    const void* W_a      = d_in[9];
    const void* b_a      = d_in[10];
    const void* W_read   = d_in[11];
    const void* b_read   = d_in[12];
    const void* W_pred   = d_in[13];
    const void* b_pred   = d_in[14];

    const long NROWS = 256L * 256L;      // 65536
    char* ws = (char*)d_ws;
    int*   flag  = (int*)  ws;
    float* accum = (float*)(ws + 64);
    float* convf = (float*)(ws + 256);
    bf16*  convb = (bf16*) (ws + 256 + CONVF_TOTAL * 4);
    size_t off = 256 + CONVF_TOTAL * 4 + CONVB_TOTAL * 2;
    bf16*  w_ws     = (bf16*)(ws + off);                 // NROWS*64 bf16
    off += NROWS * 64 * 2;
    bf16*  e_ws     = (bf16*)(ws + off);                 // NROWS*128 bf16
    off += NROWS * 128 * 2;
    bf16*  a_ws     = (bf16*)(ws + off);
    off += NROWS * 128 * 2;
    bf16*  reads_ws = (bf16*)(ws + off);

    hipMemsetAsync(accum, 0, 2 * sizeof(float), stream);

    detect_dtype<<<1, 256, 0, stream>>>(W_e, flag);
    conv_weights<<<(CONVF_TOTAL + CONVB_TOTAL + 255) / 256, 256, 0, stream>>>(
        key_mem, init_val, W_e, b_e, W_a, b_a, W_read, b_read, W_pred, b_pred,
        flag, convf, convb);
    phase1<<<NROWS / 128, 512, 0, stream>>>(q_data, qa_data, q_table, qa_table,
                                            convf, convb, flag, w_ws, e_ws, a_ws);
    phase2<<<256, 512, 0, stream>>>(q_data, convf, w_ws, e_ws, a_ws, reads_ws);
    phase3<<<NROWS / 128, 512, 0, stream>>>(q_data, q_table, reads_ws, convf, convb,
                                            target, flag, d_out, accum);
    phase4<<<1, 64, 0, stream>>>(accum, flag, d_out);
}